// Round 4
// baseline (458.292 us; speedup 1.0000x reference)
//
#include <hip/hip_runtime.h>

// Problem constants (reference: B=64, L=1024, D=1280)
#define BB 64
#define LL 1024
#define DD 1280
#define SPLITS 32       // token splits for the pool
#define CHUNK 32        // L / SPLITS
#define CC 20           // column chunks of 64 (20*64 = 1280)
#define BG 16           // b-groups of 4 (16*4 = 64)

// ---------------------------------------------------------------------------
// Kernel 1: ragged pool, fused reduction via HW f32 atomics.
// grid = (SPLITS, B) = 2048 blocks, block = 320 (5 waves) -> up to 30
// waves/CU for HBM latency hiding. Thread t owns float4 #t of each row; one
// block iteration reads one full 5120 B row, coalesced 16 B/lane. Partial
// sums are pre-scaled by 1/pool_len (distributive) and accumulated directly
// into emb[b][d] with unsafeAtomicAdd (-> global_atomic_add_f32; plain
// atomicAdd(float*) may lower to a CAS loop). Blocks past pool_len exit
// without touching memory (saves the old zero-write traffic). emb must be
// zeroed beforehand (hipMemsetAsync). Also inits out[b] = cls_b for kernel 2.
// ---------------------------------------------------------------------------
__global__ __launch_bounds__(320) void pool_atomic(
    const float* __restrict__ prev, const int* __restrict__ lengths,
    const float* __restrict__ cls_b, float* __restrict__ emb,
    float* __restrict__ out) {
  const int s = blockIdx.x;
  const int b = blockIdx.y;
  const int t = threadIdx.x;  // [0, 320)

  if (s == 0 && t == 0) out[b] = cls_b[0];

  const int pool_len = lengths[b] + 2;  // in [2, 1023]
  const int l0 = s * CHUNK;
  const int l1 = min(pool_len, l0 + CHUNK);
  if (l1 <= l0) return;  // whole split past pool_len: no reads, no atomics

  const float inv = 1.0f / (float)pool_len;
  float4 acc = make_float4(0.f, 0.f, 0.f, 0.f);
  const float* base = prev + (size_t)b * LL * DD + 4 * t;
#pragma unroll 4
  for (int l = l0; l < l1; ++l) {
    const float4 v = *(const float4*)(base + (size_t)l * DD);
    acc.x += v.x; acc.y += v.y; acc.z += v.z; acc.w += v.w;
  }
  float* e = emb + (size_t)b * DD + 4 * t;
  unsafeAtomicAdd(e + 0, acc.x * inv);
  unsafeAtomicAdd(e + 1, acc.y * inv);
  unsafeAtomicAdd(e + 2, acc.z * inv);
  unsafeAtomicAdd(e + 3, acc.w * inv);
}

// ---------------------------------------------------------------------------
// Kernel 2: per (b, col): relu(emb[b]·W[:,col] + bias[col]) * cls_w[col],
// reduced over cols into out[b] via one atomic per wave.
// grid = (CC, BG) = 320 blocks (1.25/CU), block = 256 = 4 waves. Wave w
// handles b = bg*4+w over the same 64 cols -> identical W lines across waves
// (L1 broadcast, 4x W-reuse). emb staged in LDS (broadcast reads,
// conflict-free). unroll 32 keeps 32 W loads in flight per lane.
// ---------------------------------------------------------------------------
__global__ __launch_bounds__(256) void gemm_relu_out(
    const float* __restrict__ emb, const float* __restrict__ W,
    const float* __restrict__ bias, const float* __restrict__ cls_w,
    float* __restrict__ out) {
  __shared__ float es[4 * DD];

  const int cc = blockIdx.x;
  const int bg = blockIdx.y;
  const int t = threadIdx.x;
  const int lane = t & 63;
  const int wave = t >> 6;          // 0..3 -> which b
  const int b = bg * 4 + wave;
  const int col = cc * 64 + lane;

  // Stage 4 emb rows (4*1280 floats) into LDS, coalesced.
  const float* eg = emb + (size_t)bg * 4 * DD;
  for (int i = t; i < 4 * DD; i += 256) es[i] = eg[i];
  __syncthreads();

  const float* ew = es + wave * DD;
  const float* wp = W + col;
  float acc = bias[col];
#pragma unroll 32
  for (int d = 0; d < DD; ++d) {
    acc = fmaf(ew[d], wp[(size_t)d * DD], acc);
  }
  float v = fmaxf(acc, 0.f) * cls_w[col];

  // Wave-level reduction over the 64 cols.
#pragma unroll
  for (int off = 32; off > 0; off >>= 1) v += __shfl_down(v, off);
  if (lane == 0) unsafeAtomicAdd(out + b, v);
}

extern "C" void kernel_launch(void* const* d_in, const int* in_sizes, int n_in,
                              void* d_out, int out_size, void* d_ws, size_t ws_size,
                              hipStream_t stream) {
  const float* prev    = (const float*)d_in[0];  // [B, L, D] f32
  const int*   lengths = (const int*)d_in[1];    // [B] i32
  const float* dense_w = (const float*)d_in[2];  // [D, D] f32
  const float* dense_b = (const float*)d_in[3];  // [D] f32
  const float* cls_w   = (const float*)d_in[4];  // [D, 1] f32
  const float* cls_b   = (const float*)d_in[5];  // [1] f32
  float* out = (float*)d_out;                    // [B] f32

  // Workspace: emb [B*D] floats (327 KB), zeroed each call (ws is re-poisoned
  // to 0xAA before every timed launch).
  float* emb = (float*)d_ws;
  hipMemsetAsync(emb, 0, (size_t)BB * DD * sizeof(float), stream);

  pool_atomic<<<dim3(SPLITS, BB), 320, 0, stream>>>(prev, lengths, cls_b,
                                                    emb, out);
  gemm_relu_out<<<dim3(CC, BG), 256, 0, stream>>>(emb, dense_w, dense_b,
                                                  cls_w, out);
}